// Round 9
// baseline (159.179 us; speedup 1.0000x reference)
//
#include <hip/hip_runtime.h>

typedef unsigned short u16;
typedef __attribute__((ext_vector_type(8))) short bf16x8;
typedef __attribute__((ext_vector_type(4))) float f32x4;

#define GLOAD_LDS16(gsrc, ldst)                                               \
  __builtin_amdgcn_global_load_lds(                                           \
      (const __attribute__((address_space(1))) void*)(gsrc),                  \
      (__attribute__((address_space(3))) void*)(ldst), 16, 0, 0)

#define LDSOFF(p) \
  ((unsigned)(uintptr_t)(__attribute__((address_space(3))) const void*)(p))

#define SB0 __builtin_amdgcn_sched_barrier(0)

__device__ __forceinline__ u16 f2bf(float x) {
  unsigned u = __float_as_uint(x);
  u = (u + 0x7FFFu + ((u >> 16) & 1u)) >> 16;
  return (u16)u;
}

// ---------- prep: l1/l2/l3 -> bf16 [512][288], append 1 at col 256, zero-pad ----------
__global__ void prep_l_kernel(const float* __restrict__ l1,
                              const float* __restrict__ l2,
                              const float* __restrict__ l3,
                              u16* __restrict__ o1, u16* __restrict__ o2,
                              u16* __restrict__ o3) {
  int idx = blockIdx.x * 256 + threadIdx.x;
  const int NR = 512 * 288;
  if (idx >= 3 * NR) return;
  int which = idx / NR, rem = idx - which * NR;
  int r = rem / 288, p = rem - r * 288;
  const float* s = which == 0 ? l1 : which == 1 ? l2 : l3;
  u16* d = which == 0 ? o1 : which == 1 ? o2 : o3;
  float v = (p < 256) ? s[r * 256 + p] : (p == 256 ? 1.0f : 0.0f);
  d[rem] = f2bf(v);
}

// ---------- prep: W[a][b][c] fp32 -> W2[c][b][a] bf16, zero-padded to 288 ----------
__global__ void prep_w_kernel(const float* __restrict__ W, u16* __restrict__ W2) {
  __shared__ float tile[32][33];
  const int a0 = blockIdx.x * 32, c0 = blockIdx.y * 32, b = blockIdx.z;
  const int t = threadIdx.x;
#pragma unroll
  for (int p = 0; p < 4; ++p) {
    int idx = t + p * 256;
    int cl = idx & 31, r = idx >> 5;
    int a = a0 + r, c = c0 + cl;
    float v = 0.0f;
    if (a < 257 && b < 257 && c < 257) v = W[((long)a * 257 + b) * 257 + c];
    tile[r][cl] = v;
  }
  __syncthreads();
#pragma unroll
  for (int p = 0; p < 4; ++p) {
    int idx = t + p * 256;
    int al = idx & 31, ccl = idx >> 5;
    W2[((long)(c0 + ccl) * 288 + b) * 288 + (a0 + al)] = f2bf(tile[al][ccl]);
  }
}

// ---------- stage-1 NT GEMM: 256x256 tile, 8 waves, BK=32 counted prefetch ----------
// C[512][82944] = A[512][288] * B[82944][288]^T. Grid 648 = 8 XCD x 81:
// g = xcd*81 + s; mt = g&1, nt = g>>1 -> both m-tiles of an n-tile adjacent
// on one XCD (B-tile L3-read once, L2 reuse). Race-free order per step:
// vmcnt -> barrier -> ds_reads(k) -> STG(k+1) -> partial-lgkm MFMA columns.
__global__ __launch_bounds__(512, 2) void gemm_nt(
    const u16* __restrict__ A, const u16* __restrict__ B, u16* __restrict__ C,
    int K, int lda, int ldb, int ldc) {
  __shared__ u16 As[2][8192];  // 256 rows x 32 u16 per buf
  __shared__ u16 Bs[2][8192];
  const int t = threadIdx.x;
  const int bid = blockIdx.x;
  const int xcd = bid & 7, s = bid >> 3;
  const int g = xcd * 81 + s;
  const int mt = g & 1, nt = g >> 1;
  const int m0 = mt * 256, n0 = nt * 256;
  const int lane = t & 63;
  const int w = t >> 6;            // 0..7
  const int wm = w >> 2;           // 0/1 -> m-offset *128
  const int wn = w & 3;            // 0..3 -> n-offset *64
  const int r16 = lane & 15;
  const int cgrp = lane >> 4;
  const int rr = cgrp * 4;
  const unsigned ABase = LDSOFF(&As[0][0]);
  const unsigned BBase = LDSOFF(&Bs[0][0]);
  (void)K;

  const u16* PA = A + (long)m0 * lda;
  const u16* PB = B + (long)n0 * ldb;

  // 1024 chunks per operand per step; 512 threads -> 2 A + 2 B loads/thread.
#define STG(buf, k0)                                                          \
  {                                                                           \
    _Pragma("unroll") for (int _p = 0; _p < 2; ++_p) {                        \
      int _q = t + _p * 512;                                                  \
      int _r = _q >> 2, _g = (_q & 3) ^ ((_r >> 1) & 3);                      \
      GLOAD_LDS16(PA + (long)_r * lda + (k0) + _g * 8, &As[buf][_q * 8]);     \
      GLOAD_LDS16(PB + (long)_r * ldb + (k0) + _g * 8, &Bs[buf][_q * 8]);     \
    }                                                                         \
  }

  f32x4 acc[8][4];
  const f32x4 zero = {0.f, 0.f, 0.f, 0.f};
#pragma unroll
  for (int i = 0; i < 8; ++i)
#pragma unroll
    for (int j = 0; j < 4; ++j) acc[i][j] = zero;

  STG(0, 0);

#define GCOL(NI)                                                              \
  __builtin_amdgcn_s_setprio(1);                                              \
  _Pragma("unroll") for (int _mi = 0; _mi < 8; ++_mi)                         \
    acc[_mi][NI] = __builtin_amdgcn_mfma_f32_16x16x32_bf16(                   \
        af[_mi], bf[NI], acc[_mi][NI], 0, 0, 0);                              \
  __builtin_amdgcn_s_setprio(0);                                              \
  SB0;

#define GSTEP(KS)                                                             \
  {                                                                           \
    asm volatile("s_waitcnt vmcnt(0)" ::: "memory");                          \
    SB0;                                                                      \
    __builtin_amdgcn_s_barrier();                                             \
    SB0;                                                                      \
    bf16x8 af[8], bf[4];                                                      \
    _Pragma("unroll") for (int mi = 0; mi < 8; ++mi) {                        \
      int R = wm * 128 + mi * 16 + r16;                                       \
      unsigned ao = ABase + (unsigned)(((((KS) & 1) * 8192) + R * 32 +        \
                                       ((cgrp ^ ((R >> 1) & 3)) * 8)) * 2);   \
      asm volatile("ds_read_b128 %0, %1" : "=v"(af[mi]) : "v"(ao));           \
    }                                                                         \
    _Pragma("unroll") for (int ni = 0; ni < 4; ++ni) {                        \
      int R = wn * 64 + ni * 16 + r16;                                        \
      unsigned ao = BBase + (unsigned)(((((KS) & 1) * 8192) + R * 32 +        \
                                       ((cgrp ^ ((R >> 1) & 3)) * 8)) * 2);   \
      asm volatile("ds_read_b128 %0, %1" : "=v"(bf[ni]) : "v"(ao));           \
    }                                                                         \
    SB0;                                                                      \
    if ((KS) < 8) STG(((KS) + 1) & 1, ((KS) + 1) * 32);                       \
    SB0;                                                                      \
    asm volatile("s_waitcnt lgkmcnt(3)" ::: "memory"); SB0;                   \
    GCOL(0)                                                                   \
    asm volatile("s_waitcnt lgkmcnt(2)" ::: "memory"); SB0;                   \
    GCOL(1)                                                                   \
    asm volatile("s_waitcnt lgkmcnt(1)" ::: "memory"); SB0;                   \
    GCOL(2)                                                                   \
    asm volatile("s_waitcnt lgkmcnt(0)" ::: "memory"); SB0;                   \
    GCOL(3)                                                                   \
  }

  GSTEP(0) GSTEP(1) GSTEP(2) GSTEP(3) GSTEP(4)
  GSTEP(5) GSTEP(6) GSTEP(7) GSTEP(8)
#undef GSTEP
#undef GCOL
#undef STG

#pragma unroll
  for (int mi = 0; mi < 8; ++mi) {
    int gm = m0 + wm * 128 + mi * 16 + rr;
#pragma unroll
    for (int ni = 0; ni < 4; ++ni) {
      int gc = n0 + wn * 64 + ni * 16 + r16;
#pragma unroll
      for (int r = 0; r < 4; ++r)
        C[(long)(gm + r) * ldc + gc] = f2bf(acc[mi][ni][r]);
    }
  }
}

// ---------- fused stage 2+3: counted-vmcnt 4-slab pipeline (unchanged from R8) ----------
__global__ __launch_bounds__(512, 2) void fused23(
    const u16* __restrict__ l2b, const u16* __restrict__ l3b,
    const u16* __restrict__ T1, float* __restrict__ out) {
  __shared__ u16 S[128 * 296];     // 75,776 B
  __shared__ u16 Bst[4][288 * 32]; // 73,728 B
  const int t = threadIdx.x;
  const int lane = t & 63;
  const int w = t >> 6;  // 0..7

  const int bid = blockIdx.x;  // XCD-paired: both halves of ni on one XCD
  const int xcd = bid & 7;
  const int seq = bid >> 3;
  const int ni = xcd * 64 + (seq >> 1);
  const int half = seq & 1;
  const int n = ni >> 8;

  const int r16 = lane & 15;
  const int cgrp = lane >> 4;  // 0..3
  const int kb = cgrp * 8;
  const int rr = cgrp * 4;
  const f32x4 zero = {0.f, 0.f, 0.f, 0.f};

  const u16* A2 = l2b + (long)n * 73728 + (long)(half * 128) * 288;  // [128][288]
  const u16* BT = T1 + (long)ni * 82944;                             // [288][288]
  const u16* B3 = l3b + (long)n * 73728;                             // [256][288]
  const unsigned BOF = LDSOFF(&Bst[0][0]);
  const unsigned SOF = LDSOFF(&S[0]);

#define ISSUE_A(buf, kk)                                                      \
  {                                                                           \
    int q1 = w * 144 + lane;                                                  \
    int r1 = q1 >> 2, g1 = (q1 & 3) ^ ((r1 >> 1) & 3);                        \
    GLOAD_LDS16(BT + (long)r1 * 288 + (kk) * 32 + g1 * 8, &Bst[(buf)][q1 * 8]); \
    int q2 = q1 + 64;                                                         \
    int r2 = q2 >> 2, g2 = (q2 & 3) ^ ((r2 >> 1) & 3);                        \
    GLOAD_LDS16(BT + (long)r2 * 288 + (kk) * 32 + g2 * 8, &Bst[(buf)][q2 * 8]); \
    if (lane < 16) {                                                          \
      int q3 = w * 144 + 128 + lane;                                          \
      int r3 = q3 >> 2, g3 = (q3 & 3) ^ ((r3 >> 1) & 3);                      \
      GLOAD_LDS16(BT + (long)r3 * 288 + (kk) * 32 + g3 * 8, &Bst[(buf)][q3 * 8]); \
    }                                                                         \
  }
#define ISSUE_B(buf, kk)                                                      \
  {                                                                           \
    int q1 = w * 128 + lane;                                                  \
    int r1 = q1 >> 2, g1 = (q1 & 3) ^ ((r1 >> 1) & 3);                        \
    GLOAD_LDS16(B3 + (long)r1 * 288 + (kk) * 32 + g1 * 8, &Bst[(buf)][q1 * 8]); \
    int q2 = q1 + 64;                                                         \
    int r2 = q2 >> 2, g2 = (q2 & 3) ^ ((r2 >> 1) & 3);                        \
    GLOAD_LDS16(B3 + (long)r2 * 288 + (kk) * 32 + g2 * 8, &Bst[(buf)][q2 * 8]); \
  }

  // ================= phase A =================
  {
    const int wm = w & 3, wn = w >> 2;
    f32x4 acc[2][9];
#pragma unroll
    for (int i = 0; i < 2; ++i)
#pragma unroll
      for (int j = 0; j < 9; ++j) acc[i][j] = zero;

    bf16x8 afr[18];
#pragma unroll
    for (int k = 0; k < 9; ++k)
#pragma unroll
      for (int mi = 0; mi < 2; ++mi)
        afr[k * 2 + mi] = *(const bf16x8*)(A2 +
            (long)(wm * 32 + mi * 16 + r16) * 288 + k * 32 + kb);
    SB0;

    ISSUE_A(0, 0);
    ISSUE_A(1, 1);

#define FA_MM(NJ)                                                             \
  __builtin_amdgcn_s_setprio(1);                                              \
  acc[0][NJ] = __builtin_amdgcn_mfma_f32_16x16x32_bf16(afc0, bf[NJ], acc[0][NJ], 0, 0, 0); \
  acc[1][NJ] = __builtin_amdgcn_mfma_f32_16x16x32_bf16(afc1, bf[NJ], acc[1][NJ], 0, 0, 0); \
  __builtin_amdgcn_s_setprio(0);

#define FA_STEP(K, NW)                                                        \
  {                                                                           \
    if ((K) + 2 <= 8) ISSUE_A(((K) + 2) & 3, (K) + 2);                        \
    asm volatile("s_waitcnt vmcnt(" #NW ")" ::: "memory");                    \
    SB0;                                                                      \
    __builtin_amdgcn_s_barrier();                                             \
    SB0;                                                                      \
    bf16x8 bf[9];                                                             \
    _Pragma("unroll") for (int nj = 0; nj < 9; ++nj) {                        \
      const int R = wn * 144 + nj * 16 + r16;                                 \
      unsigned ao = BOF + (unsigned)((((K) & 3) * 9216 + R * 32 +             \
                                      ((cgrp ^ ((R >> 1) & 3)) * 8)) * 2);    \
      asm volatile("ds_read_b128 %0, %1" : "=v"(bf[nj]) : "v"(ao));           \
    }                                                                         \
    SB0;                                                                      \
    const bf16x8 afc0 = afr[(K) * 2 + 0], afc1 = afr[(K) * 2 + 1];            \
    asm volatile("s_waitcnt lgkmcnt(6)" ::: "memory"); SB0;                   \
    FA_MM(0) FA_MM(1) FA_MM(2) SB0;                                           \
    asm volatile("s_waitcnt lgkmcnt(3)" ::: "memory"); SB0;                   \
    FA_MM(3) FA_MM(4) FA_MM(5) SB0;                                           \
    asm volatile("s_waitcnt lgkmcnt(0)" ::: "memory"); SB0;                   \
    FA_MM(6) FA_MM(7) FA_MM(8) SB0;                                           \
  }
    FA_STEP(0, 6) FA_STEP(1, 6) FA_STEP(2, 6) FA_STEP(3, 6) FA_STEP(4, 6)
    FA_STEP(5, 6) FA_STEP(6, 6) FA_STEP(7, 3) FA_STEP(8, 0)
#undef FA_STEP
#undef FA_MM

    __syncthreads();  // all slab reads done; Bst reusable
    ISSUE_B(0, 0);
    ISSUE_B(1, 1);
#pragma unroll
    for (int mi = 0; mi < 2; ++mi)
#pragma unroll
      for (int nj = 0; nj < 9; ++nj)
#pragma unroll
        for (int q = 0; q < 4; ++q)
          S[(wm * 32 + mi * 16 + rr + q) * 296 + wn * 144 + nj * 16 + r16] =
              f2bf(acc[mi][nj][q]);
  }
  __syncthreads();  // S visible

  // ================= phase B =================
  {
    const int wm = w & 1, wn = w >> 1;
    f32x4 acc[4][4];
#pragma unroll
    for (int i = 0; i < 4; ++i)
#pragma unroll
      for (int j = 0; j < 4; ++j) acc[i][j] = zero;

#define FB_MM(NI)                                                             \
  __builtin_amdgcn_s_setprio(1);                                              \
  acc[0][NI] = __builtin_amdgcn_mfma_f32_16x16x32_bf16(af[0], bf[NI], acc[0][NI], 0, 0, 0); \
  acc[1][NI] = __builtin_amdgcn_mfma_f32_16x16x32_bf16(af[1], bf[NI], acc[1][NI], 0, 0, 0); \
  acc[2][NI] = __builtin_amdgcn_mfma_f32_16x16x32_bf16(af[2], bf[NI], acc[2][NI], 0, 0, 0); \
  acc[3][NI] = __builtin_amdgcn_mfma_f32_16x16x32_bf16(af[3], bf[NI], acc[3][NI], 0, 0, 0); \
  __builtin_amdgcn_s_setprio(0);                                              \
  SB0;

#define FB_STEP(K, NW)                                                        \
  {                                                                           \
    if ((K) + 2 <= 8) ISSUE_B(((K) + 2) & 3, (K) + 2);                        \
    asm volatile("s_waitcnt vmcnt(" #NW ")" ::: "memory");                    \
    SB0;                                                                      \
    __builtin_amdgcn_s_barrier();                                             \
    SB0;                                                                      \
    bf16x8 af[4], bf[4];                                                      \
    _Pragma("unroll") for (int mi = 0; mi < 4; ++mi) {                        \
      unsigned ao = SOF + (unsigned)(((wm * 64 + mi * 16 + r16) * 296 +       \
                                      (K) * 32 + kb) * 2);                    \
      asm volatile("ds_read_b128 %0, %1" : "=v"(af[mi]) : "v"(ao));           \
    }                                                                         \
    _Pragma("unroll") for (int nj = 0; nj < 4; ++nj) {                        \
      const int R = wn * 64 + nj * 16 + r16;                                  \
      unsigned ao = BOF + (unsigned)((((K) & 3) * 9216 + R * 32 +             \
                                      ((cgrp ^ ((R >> 1) & 3)) * 8)) * 2);    \
      asm volatile("ds_read_b128 %0, %1" : "=v"(bf[nj]) : "v"(ao));           \
    }                                                                         \
    SB0;                                                                      \
    asm volatile("s_waitcnt lgkmcnt(3)" ::: "memory"); SB0;                   \
    FB_MM(0)                                                                  \
    asm volatile("s_waitcnt lgkmcnt(2)" ::: "memory"); SB0;                   \
    FB_MM(1)                                                                  \
    asm volatile("s_waitcnt lgkmcnt(1)" ::: "memory"); SB0;                   \
    FB_MM(2)                                                                  \
    asm volatile("s_waitcnt lgkmcnt(0)" ::: "memory"); SB0;                   \
    FB_MM(3)                                                                  \
  }
    FB_STEP(0, 4) FB_STEP(1, 4) FB_STEP(2, 4) FB_STEP(3, 4) FB_STEP(4, 4)
    FB_STEP(5, 4) FB_STEP(6, 4) FB_STEP(7, 2) FB_STEP(8, 0)
#undef FB_STEP
#undef FB_MM

    float* O = out + (long)ni * 65536 + (long)(half * 128 + wm * 64) * 256 + wn * 64;
#pragma unroll
    for (int mi = 0; mi < 4; ++mi)
#pragma unroll
      for (int nj = 0; nj < 4; ++nj)
#pragma unroll
        for (int q = 0; q < 4; ++q)
          O[(long)(mi * 16 + rr + q) * 256 + nj * 16 + r16] = acc[mi][nj][q];
  }
#undef ISSUE_A
#undef ISSUE_B
}

extern "C" void kernel_launch(void* const* d_in, const int* in_sizes, int n_in,
                              void* d_out, int out_size, void* d_ws, size_t ws_size,
                              hipStream_t stream) {
  const float* l1 = (const float*)d_in[0];
  const float* l2 = (const float*)d_in[1];
  const float* l3 = (const float*)d_in[2];
  const float* W = (const float*)d_in[3];
  float* out = (float*)d_out;
  char* ws = (char*)d_ws;

  const long LB = 512L * 288 * 2;
  u16* l1b = (u16*)ws;
  u16* l2b = (u16*)(ws + LB);
  u16* l3b = (u16*)(ws + 2 * LB);
  u16* T1 = (u16*)(ws + 3 * LB);  // [512][288c][288b] bf16 = 84.9 MB
  u16* W2 = (u16*)d_out;          // staged in d_out; dead before fused23 writes

  prep_l_kernel<<<1728, 256, 0, stream>>>(l1, l2, l3, l1b, l2b, l3b);

  dim3 gw(9, 9, 288);
  prep_w_kernel<<<gw, 256, 0, stream>>>(W, W2);

  // stage 1: T1[512][(c,b)] = l1b[512][288a] @ W2[(c,b)][288a]^T
  gemm_nt<<<648, 512, 0, stream>>>(l1b, W2, T1, 288, 288, 288, 82944);

  // fused stage 2+3: two blocks per ni, XCD-paired
  fused23<<<1024, 512, 0, stream>>>(l2b, l3b, T1, out);
}